// Round 11
// baseline (867.758 us; speedup 1.0000x reference)
//
#include <hip/hip_runtime.h>

// obj = (99*sum_t ||c_t||^2 + ||sum_t c_t||^2)/100 (Parseval over 100 samples
// = 99th roots of unity, z=1 double-counted), c_0 = D_F,
// c_{k+1} = E_k = C_F A_F^k B_F - C A^k B, B = eye(256,128), K=8 terms.
// Double-step with bf16 constant slabs (round-9 numerics, cross-term bug FIXED):
//   pre1: split-K(4) fp32 partials of A2=AF^2, W1=AF*BF, AH2=A^2
//   pre2: resolve partials -> packed bf16 (r | i<<16); convert BF, A
//   dstep s (s=0..3): Ee_s = QF*BFb - QH[:,:128]  (E_{2s})
//                     Eo_s = QF*W1b - QH*Ab[:,:128] (E_{2s+1})
//                     QF <- QF*A2b, QH <- QH*AH2b  (fan-in-8 split-K partials,
//                     resolved during next dispatch's staging)
//   finalize: resolve E_7 pair, S1/S2/SD atomics, ticketed out-write.
// Inner loop: 32x128 block tile, 4 rows x 4 cols per thread: per k 2 Q-b128 +
// 1 B-uint4 LDS reads feed 64 FMA (was 2 reads : 16 FMA) — attacks the
// measured 12.5 TF dependency-bound ceiling. 7 dispatches. ws 18.4 MB.

struct Params {
    const float *AFr, *AFi, *Ar, *Ai, *BFr, *BFi, *CFr, *CFi, *Cr, *Ci, *DFr, *DFi;
    float2 *A2p, *W1p, *AH2p;                    // pre1 partials (x4), overlaid
    unsigned int *A2b, *W1b, *AH2b, *BFb, *Ab;   // packed bf16 constants
    float2 *QFp0, *QFp1, *QHp0, *QHp1, *Eep0, *Eep1, *Eop0, *Eop1, *Sm;
    float *S1, *S2, *SD; unsigned int *ticket;
    float *out;
};

#define UNPACK_R(u) __uint_as_float((u) << 16)
#define UNPACK_I(u) __uint_as_float((u) & 0xffff0000u)

__device__ __forceinline__ unsigned int f2bf2(float r, float i) {
    unsigned int ur = __float_as_uint(r); ur = (ur + 0x7fffu + ((ur >> 16) & 1u)) >> 16;
    unsigned int ui = __float_as_uint(i); ui = (ui + 0x7fffu + ((ui >> 16) & 1u)) >> 16;
    return ur | (ui << 16);
}

__device__ __forceinline__ float block_reduce(float v, float* red, int tid) {
    red[tid] = v;
    __syncthreads();
    for (int off = 128; off > 0; off >>= 1) {
        if (tid < off) red[tid] += red[tid + off];
        __syncthreads();
    }
    float r = red[0];
    __syncthreads();
    return r;
}

__device__ __forceinline__ void store16(float2* O, int Wo, int prow0, int pcol0,
                                        const float* accr, const float* acci, float sgn) {
    #pragma unroll
    for (int r = 0; r < 4; ++r) {
        float2* p = &O[(prow0 + r) * Wo + pcol0];
        ((float4*)p)[0] = make_float4(sgn * accr[4*r],     sgn * acci[4*r],
                                      sgn * accr[4*r + 1], sgn * acci[4*r + 1]);
        ((float4*)p)[1] = make_float4(sgn * accr[4*r + 2], sgn * acci[4*r + 2],
                                      sgn * accr[4*r + 3], sgn * acci[4*r + 3]);
    }
}

// ---------------- pre1: fp32 GEMM, 32x128 tile, 4x4 micro, windowed Q -------
template<int KD>
__device__ __forceinline__ void dgemm_fp(
    const float* __restrict__ Br_, const float* __restrict__ Bi_, int Wb, int c0, int k0,
    const float* __restrict__ Qr_, const float* __restrict__ Qi_, int Wq, int rg,
    float2 (*sB)[128], float2 (*sQ)[33], float* accr, float* acci) {
    const int tid = threadIdx.x;
    const int rw = tid >> 5, cp = tid & 31;
    const int c4 = 4 * cp;
    float4 pb[4];
    auto loadB = [&](int c) {
        int gk = k0 + c * 16 + rw;
        pb[0] = *(const float4*)&Br_[gk * Wb + c0 + c4];
        pb[1] = *(const float4*)&Bi_[gk * Wb + c0 + c4];
        pb[2] = *(const float4*)&Br_[(gk + 8) * Wb + c0 + c4];
        pb[3] = *(const float4*)&Bi_[(gk + 8) * Wb + c0 + c4];
    };
    auto commitB = [&]() {
        float2* p0 = &sB[rw][c4];
        ((float4*)p0)[0] = make_float4(pb[0].x, pb[1].x, pb[0].y, pb[1].y);
        ((float4*)p0)[1] = make_float4(pb[0].z, pb[1].z, pb[0].w, pb[1].w);
        float2* p1 = &sB[rw + 8][c4];
        ((float4*)p1)[0] = make_float4(pb[2].x, pb[3].x, pb[2].y, pb[3].y);
        ((float4*)p1)[1] = make_float4(pb[2].z, pb[3].z, pb[2].w, pb[3].w);
    };
    loadB(0);
    #pragma unroll
    for (int c = 0; c < KD / 16; ++c) {
        __syncthreads();
        if ((c % 3) == 0) {               // stage Q window [16c, 16c+wlen)
            int w0 = 16 * c;
            int wlen = KD - w0; if (wlen > 48) wlen = 48;
            for (int slot = tid; slot < 32 * wlen; slot += 256) {
                int row = slot / wlen, kk = slot - row * wlen;
                int g = (rg * 32 + row) * Wq + k0 + w0 + kk;
                sQ[kk][row] = make_float2(Qr_[g], Qi_[g]);
            }
        }
        commitB();
        __syncthreads();
        if (c + 1 < KD / 16) loadB(c + 1);
        const int kb = (c % 3) * 16;
        #pragma unroll
        for (int kk = 0; kk < 16; ++kk) {
            float4 qA = *(const float4*)&sQ[kb + kk][4 * rw];
            float4 qB = *(const float4*)&sQ[kb + kk][4 * rw + 2];
            float4 b0 = *(const float4*)&sB[kk][c4];
            float4 b1 = *(const float4*)&sB[kk][c4 + 2];
            float qr[4] = {qA.x, qA.z, qB.x, qB.z};
            float qi[4] = {qA.y, qA.w, qB.y, qB.w};
            float br[4] = {b0.x, b0.z, b1.x, b1.z};
            float bi[4] = {b0.y, b0.w, b1.y, b1.w};
            #pragma unroll
            for (int r = 0; r < 4; ++r)
                #pragma unroll
                for (int cc = 0; cc < 4; ++cc) {
                    accr[4*r + cc] += qr[r] * br[cc] - qi[r] * bi[cc];
                    acci[4*r + cc] += qr[r] * bi[cc] + qi[r] * br[cc];
                }
        }
    }
}

// 256 blocks: [0,144) A2 = AF*AF (12rg x 3cs x 4part, KD96);
//             [144,192) W1 = AF*BF (12rg x 4part, KD96);
//             [192,256) AH2 = A*A (8rg x 2cs x 4part, KD64)
__global__ __launch_bounds__(256, 2)
void pre1_kernel(Params P) {
    __shared__ __align__(16) float2 sB[16][128];
    __shared__ __align__(16) float2 sQ[48][33];
    const int b = blockIdx.x, tid = threadIdx.x;
    const int rw = tid >> 5, cp = tid & 31;
    float accr[16] = {}, acci[16] = {};
    int rg, c0, Wo; float2* O;
    if (b < 144) {
        int tile = b >> 2, part = b & 3;
        rg = tile / 3; int cs = tile - 3 * rg; c0 = cs << 7; Wo = 384;
        dgemm_fp<96>(P.AFr, P.AFi, 384, c0, part * 96, P.AFr, P.AFi, 384, rg, sB, sQ, accr, acci);
        O = P.A2p + part * 147456;
    } else if (b < 192) {
        int u = b - 144, part = u & 3;
        rg = u >> 2; c0 = 0; Wo = 128;
        dgemm_fp<96>(P.BFr, P.BFi, 128, 0, part * 96, P.AFr, P.AFi, 384, rg, sB, sQ, accr, acci);
        O = P.W1p + part * 49152;
    } else {
        int u = b - 192, tile = u >> 2, part = u & 3;
        rg = tile >> 1; int cs = tile & 1; c0 = cs << 7; Wo = 256;
        dgemm_fp<64>(P.Ar, P.Ai, 256, c0, part * 64, P.Ar, P.Ai, 256, rg, sB, sQ, accr, acci);
        O = P.AH2p + part * 65536;
    }
    store16(O, Wo, rg * 32 + 4 * rw, c0 + 4 * cp, accr, acci, 1.f);
}

// ------------- pre2: resolve pre1 partials -> bf16; convert BF, A -----------
__global__ __launch_bounds__(256)
void pre2_kernel(Params P) {
    int idx = blockIdx.x * 256 + threadIdx.x;
    if (idx < 147456) {
        float2 a = P.A2p[idx], b = P.A2p[147456 + idx];
        float2 c = P.A2p[294912 + idx], d = P.A2p[442368 + idx];
        P.A2b[idx] = f2bf2(a.x + b.x + c.x + d.x, a.y + b.y + c.y + d.y);
    } else if (idx < 196608) {
        int j = idx - 147456;
        float2 a = P.W1p[j], b = P.W1p[49152 + j];
        float2 c = P.W1p[98304 + j], d = P.W1p[147456 + j];
        P.W1b[j] = f2bf2(a.x + b.x + c.x + d.x, a.y + b.y + c.y + d.y);
    } else if (idx < 262144) {
        int j = idx - 196608;
        float2 a = P.AH2p[j], b = P.AH2p[65536 + j];
        float2 c = P.AH2p[131072 + j], d = P.AH2p[196608 + j];
        P.AH2b[j] = f2bf2(a.x + b.x + c.x + d.x, a.y + b.y + c.y + d.y);
    } else if (idx < 311296) {
        int j = idx - 262144;
        P.BFb[j] = f2bf2(P.BFr[j], P.BFi[j]);
    } else if (idx < 376832) {
        int j = idx - 311296;
        P.Ab[j] = f2bf2(P.Ar[j], P.Ai[j]);
    }
}

// ------------- dstep GEMM: fp32 Q x bf16 B, 32x128 tile, 4x4 micro ----------
template<int KD>
__device__ __forceinline__ void dgemm_bf(
    const unsigned int* __restrict__ Bb, int Wb, int c0, int k0,
    const float* __restrict__ Q0r, const float* __restrict__ Q0i,
    const float2* __restrict__ Qrd, int QD, int first, int rg,
    unsigned int (*sBu)[128], float2 (*sQ)[33], float* accr, float* acci) {
    const int tid = threadIdx.x;
    const int rw = tid >> 5, cp = tid & 31;
    const int c4 = 4 * cp;
    // step-invariant bf16 B slab -> registers
    uint4 rb[KD / 8];
    #pragma unroll
    for (int j = 0; j < KD / 8; ++j)
        rb[j] = *(const uint4*)&Bb[(k0 + rw + 8 * j) * Wb + c0 + c4];
    // stage Q rows rg*32..+31 over [k0,k0+KD), fan-in-8 resolve
    const int qsz = QD << 7;
    #pragma unroll
    for (int j = 0; j < (KD * 32) / 256; ++j) {
        int slot = j * 256 + tid;
        int row = slot / KD, kk = slot - row * KD;
        int g = (rg * 32 + row) * QD + k0 + kk;
        float2 q;
        if (first) {
            q = make_float2(Q0r[g], Q0i[g]);
        } else {
            q = make_float2(0.f, 0.f);
            #pragma unroll
            for (int pt = 0; pt < 8; ++pt) {
                float2 v = Qrd[pt * qsz + g];
                q.x += v.x; q.y += v.y;
            }
        }
        sQ[kk][row] = q;
    }
    #pragma unroll
    for (int c = 0; c < KD / 16; ++c) {
        __syncthreads();
        *(uint4*)&sBu[rw][c4]     = rb[2 * c];
        *(uint4*)&sBu[rw + 8][c4] = rb[2 * c + 1];
        __syncthreads();
        #pragma unroll
        for (int kk = 0; kk < 16; ++kk) {
            float4 qA = *(const float4*)&sQ[c * 16 + kk][4 * rw];
            float4 qB = *(const float4*)&sQ[c * 16 + kk][4 * rw + 2];
            uint4 bu = *(const uint4*)&sBu[kk][c4];
            float qr[4] = {qA.x, qA.z, qB.x, qB.z};
            float qi[4] = {qA.y, qA.w, qB.y, qB.w};
            float br[4] = {UNPACK_R(bu.x), UNPACK_R(bu.y), UNPACK_R(bu.z), UNPACK_R(bu.w)};
            float bi[4] = {UNPACK_I(bu.x), UNPACK_I(bu.y), UNPACK_I(bu.z), UNPACK_I(bu.w)};
            #pragma unroll
            for (int r = 0; r < 4; ++r)
                #pragma unroll
                for (int cc = 0; cc < 4; ++cc) {
                    accr[4*r + cc] += qr[r] * br[cc] - qi[r] * bi[cc];
                    acci[4*r + cc] += qr[r] * bi[cc] + qi[r] * br[cc];
                }
        }
    }
}

// Grid 256 (full): [0,96) F: QF*A2b (4rg x 3cs x 8part, KD48)
//  [96,128)  Ee:  QF*BFb (4rg x 8part, KD48); part0 subtracts resolved
//            QH[:,:128]; ALL Ee blocks: resolve E_{s-1} pair -> Sm/S1 (init s=0)
//  [128,160) Eo1: QF*W1b -> Eo parts 0..7
//  [160,192) Eo2: -QH*Ab[:,:128] (KD32) -> Eo parts 8..15
//  [192,256) H:   QH*AH2b (4rg x 2cs x 8part, KD32)
__global__ __launch_bounds__(256, 2)
void dstep_kernel(Params P, int s, int base) {
    __shared__ __align__(16) unsigned int sBu[16][128];  // 8 KB
    __shared__ __align__(16) float2 sQ[48][33];          // 12.7 KB
    __shared__ float red[256];
    const int b = blockIdx.x + base, tid = threadIdx.x;
    const int rw = tid >> 5, cp = tid & 31;

    const float2* QFrd = (s & 1) ? P.QFp1 : P.QFp0;
    float2*       QFwr = (s & 1) ? P.QFp0 : P.QFp1;
    const float2* QHrd = (s & 1) ? P.QHp1 : P.QHp0;
    float2*       QHwr = (s & 1) ? P.QHp0 : P.QHp1;
    const float2* Eerd = (s & 1) ? P.Eep1 : P.Eep0;
    float2*       Eewr = (s & 1) ? P.Eep0 : P.Eep1;
    const float2* Eord = (s & 1) ? P.Eop1 : P.Eop0;
    float2*       Eowr = (s & 1) ? P.Eop0 : P.Eop1;
    const int first = (s == 0);

    float accr[16] = {}, acci[16] = {};

    if (b < 96) {                        // ---- F: QF*A2b
        int tile = b >> 3, part = b & 7;
        int rg = tile / 3, cs = tile - 3 * rg;
        dgemm_bf<48>(P.A2b, 384, cs << 7, part * 48, P.CFr, P.CFi, QFrd, 384,
                     first, rg, sBu, sQ, accr, acci);
        store16(QFwr + part * 49152, 384, rg * 32 + 4 * rw, (cs << 7) + 4 * cp, accr, acci, 1.f);
    } else if (b < 128) {                // ---- Ee: QF*BFb (+duties)
        int u = b - 96, rg = u >> 3, part = u & 7;
        // duty: resolve E_{s-1} pair into Sm/S1 (E_even, E_odd squared separately)
        if (first) {
            #pragma unroll
            for (int j = 0; j < 2; ++j) {
                int i = u * 512 + j * 256 + tid;
                P.Sm[i] = make_float2(P.DFr[i], P.DFi[i]);
            }
            if (b == 96 && tid == 0) { *P.S1 = 0.f; *P.S2 = 0.f; *P.SD = 0.f; *P.ticket = 0u; }
        } else {
            float v = 0.f;
            #pragma unroll
            for (int j = 0; j < 2; ++j) {
                int i = u * 512 + j * 256 + tid;
                float eer = 0.f, eei = 0.f, eor = 0.f, eoi = 0.f;
                #pragma unroll
                for (int pt = 0; pt < 8; ++pt) {
                    float2 e = Eerd[pt * 16384 + i];
                    eer += e.x; eei += e.y;
                }
                #pragma unroll
                for (int pt = 0; pt < 16; ++pt) {
                    float2 e = Eord[pt * 16384 + i];
                    eor += e.x; eoi += e.y;
                }
                float2 sm = P.Sm[i];
                P.Sm[i] = make_float2(sm.x + eer + eor, sm.y + eei + eoi);
                v += eer * eer + eei * eei + eor * eor + eoi * eoi;
            }
            float tot = block_reduce(v, red, tid);
            if (tid == 0) atomicAdd(P.S1, tot);
        }
        dgemm_bf<48>(P.BFb, 128, 0, part * 48, P.CFr, P.CFi, QFrd, 384,
                     first, rg, sBu, sQ, accr, acci);
        const int prow0 = rg * 32 + 4 * rw, pcol0 = 4 * cp;
        if (part == 0) {   // subtract resolved QH[:, :128] exactly once
            #pragma unroll
            for (int r = 0; r < 4; ++r) {
                int gbase = (prow0 + r) * 256 + pcol0;
                if (first) {
                    #pragma unroll
                    for (int cc = 0; cc < 4; ++cc) {
                        accr[4*r + cc] -= P.Cr[gbase + cc];
                        acci[4*r + cc] -= P.Ci[gbase + cc];
                    }
                } else {
                    #pragma unroll
                    for (int pt = 0; pt < 8; ++pt) {
                        const float2* qh = QHrd + pt * 32768;
                        #pragma unroll
                        for (int cc = 0; cc < 4; ++cc) {
                            float2 v = qh[gbase + cc];
                            accr[4*r + cc] -= v.x; acci[4*r + cc] -= v.y;
                        }
                    }
                }
            }
        }
        store16(Eewr + part * 16384, 128, prow0, pcol0, accr, acci, 1.f);
    } else if (b < 160) {                // ---- Eo1: QF*W1b
        int u = b - 128, rg = u >> 3, part = u & 7;
        dgemm_bf<48>(P.W1b, 128, 0, part * 48, P.CFr, P.CFi, QFrd, 384,
                     first, rg, sBu, sQ, accr, acci);
        store16(Eowr + part * 16384, 128, rg * 32 + 4 * rw, 4 * cp, accr, acci, 1.f);
    } else if (b < 192) {                // ---- Eo2: -QH*Ab[:, :128]
        int u = b - 160, rg = u >> 3, part = u & 7;
        dgemm_bf<32>(P.Ab, 256, 0, part * 32, P.Cr, P.Ci, QHrd, 256,
                     first, rg, sBu, sQ, accr, acci);
        store16(Eowr + (8 + part) * 16384, 128, rg * 32 + 4 * rw, 4 * cp, accr, acci, -1.f);
    } else {                             // ---- H: QH*AH2b
        int u = b - 192, tile = u >> 3, part = u & 7;
        int rg = tile >> 1, cs = tile & 1;
        dgemm_bf<32>(P.AH2b, 256, cs << 7, part * 32, P.Cr, P.Ci, QHrd, 256,
                     first, rg, sBu, sQ, accr, acci);
        store16(QHwr + part * 32768, 256, rg * 32 + 4 * rw, (cs << 7) + 4 * cp, accr, acci, 1.f);
    }
}

// --------- finalize: resolve E_7 pair, S1/S2/SD, ticketed out-write ---------
__global__ __launch_bounds__(256)
void finalize_kernel(Params P) {
    __shared__ float red[256];
    __shared__ unsigned int lastflag;
    const int b = blockIdx.x, tid = threadIdx.x;
    int i = (b << 8) + tid;
    float eer = 0.f, eei = 0.f, eor = 0.f, eoi = 0.f;
    #pragma unroll
    for (int pt = 0; pt < 8; ++pt) { float2 e = P.Eep0[pt * 16384 + i]; eer += e.x; eei += e.y; }
    #pragma unroll
    for (int pt = 0; pt < 16; ++pt) { float2 e = P.Eop0[pt * 16384 + i]; eor += e.x; eoi += e.y; }
    float2 sm = P.Sm[i];
    float smr = sm.x + eer + eor, smi = sm.y + eei + eoi;
    float dr = P.DFr[i], di = P.DFi[i];
    float t1 = block_reduce(eer * eer + eei * eei + eor * eor + eoi * eoi, red, tid);
    if (tid == 0) atomicAdd(P.S1, t1);
    float t2 = block_reduce(smr * smr + smi * smi, red, tid);
    if (tid == 0) atomicAdd(P.S2, t2);
    float t3 = block_reduce(dr * dr + di * di, red, tid);
    if (tid == 0) atomicAdd(P.SD, t3);
    __threadfence();
    __syncthreads();
    if (tid == 0)
        lastflag = (__hip_atomic_fetch_add(P.ticket, 1u, __ATOMIC_ACQ_REL,
                                           __HIP_MEMORY_SCOPE_AGENT) == 63u);
    __syncthreads();
    if (lastflag && tid == 0) {
        float S1 = __hip_atomic_load(P.S1, __ATOMIC_RELAXED, __HIP_MEMORY_SCOPE_AGENT);
        float S2 = __hip_atomic_load(P.S2, __ATOMIC_RELAXED, __HIP_MEMORY_SCOPE_AGENT);
        float SD = __hip_atomic_load(P.SD, __ATOMIC_RELAXED, __HIP_MEMORY_SCOPE_AGENT);
        P.out[0] = (99.0f * (S1 + SD) + S2) / 100.0f;
    }
}

extern "C" void kernel_launch(void* const* d_in, const int* in_sizes, int n_in,
                              void* d_out, int out_size, void* d_ws, size_t ws_size,
                              hipStream_t stream) {
    (void)in_sizes; (void)n_in; (void)out_size; (void)ws_size;
    char* ws = (char*)d_ws;
    Params h;
    h.Cr  = (const float*)d_in[0];
    h.Ci  = (const float*)d_in[1];
    h.Ar  = (const float*)d_in[2];
    h.Ai  = (const float*)d_in[3];
    h.AFr = (const float*)d_in[4];
    h.AFi = (const float*)d_in[5];
    h.BFr = (const float*)d_in[6];
    h.BFi = (const float*)d_in[7];
    h.CFr = (const float*)d_in[8];
    h.CFi = (const float*)d_in[9];
    h.DFr = (const float*)d_in[10];
    h.DFi = (const float*)d_in[11];
    // Region A [0, 8388608): pre1 partials, later overlaid by the p0 buffers
    // (pre partials are dead after pre2; p0 set first written at s=1).
    h.A2p  = (float2*)(ws + 0);          // 4*147456 f2 = 4718592 B
    h.W1p  = (float2*)(ws + 4718592);    // 4*49152  f2 = 1572864 B
    h.AH2p = (float2*)(ws + 6291456);    // 4*65536  f2 = 2097152 B
    h.QFp0 = (float2*)(ws + 0);          // 8*49152 f2 = 3145728 B
    h.QHp0 = (float2*)(ws + 3145728);    // 8*32768 f2 = 2097152 B
    h.Eep0 = (float2*)(ws + 5242880);    // 8*16384 f2 = 1048576 B
    h.Eop0 = (float2*)(ws + 6291456);    // 16*16384 f2 = 2097152 B
    // Region B [8388608, ...): persistent
    h.A2b  = (unsigned int*)(ws + 8388608);   // 589824
    h.W1b  = (unsigned int*)(ws + 8978432);   // 196608
    h.AH2b = (unsigned int*)(ws + 9175040);   // 262144
    h.BFb  = (unsigned int*)(ws + 9437184);   // 196608
    h.Ab   = (unsigned int*)(ws + 9633792);   // 262144
    h.QFp1 = (float2*)(ws + 9895936);         // 3145728
    h.QHp1 = (float2*)(ws + 13041664);        // 2097152
    h.Eep1 = (float2*)(ws + 15138816);        // 1048576
    h.Eop1 = (float2*)(ws + 16187392);        // 2097152
    h.Sm   = (float2*)(ws + 18284544);        // 131072
    h.S1   = (float*)(ws + 18415616);
    h.S2   = (float*)(ws + 18415620);
    h.SD   = (float*)(ws + 18415624);
    h.ticket = (unsigned int*)(ws + 18415628);
    h.out  = (float*)d_out;

    pre1_kernel<<<256, 256, 0, stream>>>(h);
    pre2_kernel<<<1472, 256, 0, stream>>>(h);
    for (int s = 0; s < 3; ++s)
        dstep_kernel<<<256, 256, 0, stream>>>(h, s, 0);
    // last double-step: E sections only (QF/QH advance would be dead work)
    dstep_kernel<<<96, 256, 0, stream>>>(h, 3, 96);
    finalize_kernel<<<64, 256, 0, stream>>>(h);
}

// Round 12
// 229.085 us; speedup vs baseline: 3.7879x; 3.7879x over previous
//
#include <hip/hip_runtime.h>

// obj = (99*sum_t ||c_t||^2 + ||sum_t c_t||^2)/100 (Parseval over 100 samples
// = 99th roots of unity, z=1 double-counted), c_0 = D_F,
// c_{k+1} = E_k = C_F A_F^k B_F - C A^k B, B = eye(256,128), K=8 terms.
// Double-step with bf16 constant slabs:
//   pre1: split-K(4) fp32 partials of A2=AF^2, W1=AF*BF, AH2=A^2
//   pre2: resolve partials -> packed bf16 (r | i<<16); convert BF, A
//   dstep s (s=0..3): Ee_s = QF*BFb - QH[:,:128]  (E_{2s})
//                     Eo_s = QF*W1b - QH*Ab[:,:128] (E_{2s+1})
//                     QF <- QF*A2b, QH <- QH*AH2b  (fan-in-8 split-K partials,
//                     resolved during next dispatch's staging)
//   finalize: resolve E_7 pair, S1/S2/SD atomics, ticketed out-write.
// 32x128 block tile, 4x4 micro (64 FMA per 3 LDS reads, 32 indep acc chains).
// ROUND-12 FIX: __launch_bounds__(256,1) — round 11's (256,2) capped VGPR at
// 128 and spilled the accumulators to scratch (500 MB WRITE_SIZE, 527 us pre1).
// 7 dispatches. ws 18.4 MB.

struct Params {
    const float *AFr, *AFi, *Ar, *Ai, *BFr, *BFi, *CFr, *CFi, *Cr, *Ci, *DFr, *DFi;
    float2 *A2p, *W1p, *AH2p;                    // pre1 partials (x4), overlaid
    unsigned int *A2b, *W1b, *AH2b, *BFb, *Ab;   // packed bf16 constants
    float2 *QFp0, *QFp1, *QHp0, *QHp1, *Eep0, *Eep1, *Eop0, *Eop1, *Sm;
    float *S1, *S2, *SD; unsigned int *ticket;
    float *out;
};

#define UNPACK_R(u) __uint_as_float((u) << 16)
#define UNPACK_I(u) __uint_as_float((u) & 0xffff0000u)

__device__ __forceinline__ unsigned int f2bf2(float r, float i) {
    unsigned int ur = __float_as_uint(r); ur = (ur + 0x7fffu + ((ur >> 16) & 1u)) >> 16;
    unsigned int ui = __float_as_uint(i); ui = (ui + 0x7fffu + ((ui >> 16) & 1u)) >> 16;
    return ur | (ui << 16);
}

__device__ __forceinline__ float block_reduce(float v, float* red, int tid) {
    red[tid] = v;
    __syncthreads();
    for (int off = 128; off > 0; off >>= 1) {
        if (tid < off) red[tid] += red[tid + off];
        __syncthreads();
    }
    float r = red[0];
    __syncthreads();
    return r;
}

__device__ __forceinline__ void store16(float2* O, int Wo, int prow0, int pcol0,
                                        const float* accr, const float* acci, float sgn) {
    #pragma unroll
    for (int r = 0; r < 4; ++r) {
        float2* p = &O[(prow0 + r) * Wo + pcol0];
        ((float4*)p)[0] = make_float4(sgn * accr[4*r],     sgn * acci[4*r],
                                      sgn * accr[4*r + 1], sgn * acci[4*r + 1]);
        ((float4*)p)[1] = make_float4(sgn * accr[4*r + 2], sgn * acci[4*r + 2],
                                      sgn * accr[4*r + 3], sgn * acci[4*r + 3]);
    }
}

// ---------------- pre1: fp32 GEMM, 32x128 tile, 4x4 micro, windowed Q -------
template<int KD>
__device__ __forceinline__ void dgemm_fp(
    const float* __restrict__ Br_, const float* __restrict__ Bi_, int Wb, int c0, int k0,
    const float* __restrict__ Qr_, const float* __restrict__ Qi_, int Wq, int rg,
    float2 (*sB)[128], float2 (*sQ)[33], float* accr, float* acci) {
    const int tid = threadIdx.x;
    const int rw = tid >> 5, cp = tid & 31;
    const int c4 = 4 * cp;
    float4 pb[4];
    auto loadB = [&](int c) {
        int gk = k0 + c * 16 + rw;
        pb[0] = *(const float4*)&Br_[gk * Wb + c0 + c4];
        pb[1] = *(const float4*)&Bi_[gk * Wb + c0 + c4];
        pb[2] = *(const float4*)&Br_[(gk + 8) * Wb + c0 + c4];
        pb[3] = *(const float4*)&Bi_[(gk + 8) * Wb + c0 + c4];
    };
    auto commitB = [&]() {
        float2* p0 = &sB[rw][c4];
        ((float4*)p0)[0] = make_float4(pb[0].x, pb[1].x, pb[0].y, pb[1].y);
        ((float4*)p0)[1] = make_float4(pb[0].z, pb[1].z, pb[0].w, pb[1].w);
        float2* p1 = &sB[rw + 8][c4];
        ((float4*)p1)[0] = make_float4(pb[2].x, pb[3].x, pb[2].y, pb[3].y);
        ((float4*)p1)[1] = make_float4(pb[2].z, pb[3].z, pb[2].w, pb[3].w);
    };
    loadB(0);
    for (int c = 0; c < KD / 16; ++c) {
        __syncthreads();
        if ((c % 3) == 0) {               // stage Q window [16c, 16c+wlen)
            int w0 = 16 * c;
            int wlen = KD - w0; if (wlen > 48) wlen = 48;
            for (int slot = tid; slot < 32 * wlen; slot += 256) {
                int row = slot / wlen, kk = slot - row * wlen;
                int g = (rg * 32 + row) * Wq + k0 + w0 + kk;
                sQ[kk][row] = make_float2(Qr_[g], Qi_[g]);
            }
        }
        commitB();
        __syncthreads();
        if (c + 1 < KD / 16) loadB(c + 1);
        const int kb = (c % 3) * 16;
        #pragma unroll
        for (int kk = 0; kk < 16; ++kk) {
            float4 qA = *(const float4*)&sQ[kb + kk][4 * rw];
            float4 qB = *(const float4*)&sQ[kb + kk][4 * rw + 2];
            float4 b0 = *(const float4*)&sB[kk][c4];
            float4 b1 = *(const float4*)&sB[kk][c4 + 2];
            float qr[4] = {qA.x, qA.z, qB.x, qB.z};
            float qi[4] = {qA.y, qA.w, qB.y, qB.w};
            float br[4] = {b0.x, b0.z, b1.x, b1.z};
            float bi[4] = {b0.y, b0.w, b1.y, b1.w};
            #pragma unroll
            for (int r = 0; r < 4; ++r)
                #pragma unroll
                for (int cc = 0; cc < 4; ++cc) {
                    accr[4*r + cc] += qr[r] * br[cc] - qi[r] * bi[cc];
                    acci[4*r + cc] += qr[r] * bi[cc] + qi[r] * br[cc];
                }
        }
    }
}

// 256 blocks: [0,144) A2 = AF*AF (12rg x 3cs x 4part, KD96);
//             [144,192) W1 = AF*BF (12rg x 4part, KD96);
//             [192,256) AH2 = A*A (8rg x 2cs x 4part, KD64)
__global__ __launch_bounds__(256, 1)
void pre1_kernel(Params P) {
    __shared__ __align__(16) float2 sB[16][128];
    __shared__ __align__(16) float2 sQ[48][33];
    const int b = blockIdx.x, tid = threadIdx.x;
    const int rw = tid >> 5, cp = tid & 31;
    float accr[16] = {}, acci[16] = {};
    int rg, c0, Wo; float2* O;
    if (b < 144) {
        int tile = b >> 2, part = b & 3;
        rg = tile / 3; int cs = tile - 3 * rg; c0 = cs << 7; Wo = 384;
        dgemm_fp<96>(P.AFr, P.AFi, 384, c0, part * 96, P.AFr, P.AFi, 384, rg, sB, sQ, accr, acci);
        O = P.A2p + part * 147456;
    } else if (b < 192) {
        int u = b - 144, part = u & 3;
        rg = u >> 2; c0 = 0; Wo = 128;
        dgemm_fp<96>(P.BFr, P.BFi, 128, 0, part * 96, P.AFr, P.AFi, 384, rg, sB, sQ, accr, acci);
        O = P.W1p + part * 49152;
    } else {
        int u = b - 192, tile = u >> 2, part = u & 3;
        rg = tile >> 1; int cs = tile & 1; c0 = cs << 7; Wo = 256;
        dgemm_fp<64>(P.Ar, P.Ai, 256, c0, part * 64, P.Ar, P.Ai, 256, rg, sB, sQ, accr, acci);
        O = P.AH2p + part * 65536;
    }
    store16(O, Wo, rg * 32 + 4 * rw, c0 + 4 * cp, accr, acci, 1.f);
}

// ------------- pre2: resolve pre1 partials -> bf16; convert BF, A -----------
__global__ __launch_bounds__(256)
void pre2_kernel(Params P) {
    int idx = blockIdx.x * 256 + threadIdx.x;
    if (idx < 147456) {
        float2 a = P.A2p[idx], b = P.A2p[147456 + idx];
        float2 c = P.A2p[294912 + idx], d = P.A2p[442368 + idx];
        P.A2b[idx] = f2bf2(a.x + b.x + c.x + d.x, a.y + b.y + c.y + d.y);
    } else if (idx < 196608) {
        int j = idx - 147456;
        float2 a = P.W1p[j], b = P.W1p[49152 + j];
        float2 c = P.W1p[98304 + j], d = P.W1p[147456 + j];
        P.W1b[j] = f2bf2(a.x + b.x + c.x + d.x, a.y + b.y + c.y + d.y);
    } else if (idx < 262144) {
        int j = idx - 196608;
        float2 a = P.AH2p[j], b = P.AH2p[65536 + j];
        float2 c = P.AH2p[131072 + j], d = P.AH2p[196608 + j];
        P.AH2b[j] = f2bf2(a.x + b.x + c.x + d.x, a.y + b.y + c.y + d.y);
    } else if (idx < 311296) {
        int j = idx - 262144;
        P.BFb[j] = f2bf2(P.BFr[j], P.BFi[j]);
    } else if (idx < 376832) {
        int j = idx - 311296;
        P.Ab[j] = f2bf2(P.Ar[j], P.Ai[j]);
    }
}

// ------------- dstep GEMM: fp32 Q x bf16 B, 32x128 tile, 4x4 micro ----------
template<int KD>
__device__ __forceinline__ void dgemm_bf(
    const unsigned int* __restrict__ Bb, int Wb, int c0, int k0,
    const float* __restrict__ Q0r, const float* __restrict__ Q0i,
    const float2* __restrict__ Qrd, int QD, int first, int rg,
    unsigned int (*sBu)[128], float2 (*sQ)[33], float* accr, float* acci) {
    const int tid = threadIdx.x;
    const int rw = tid >> 5, cp = tid & 31;
    const int c4 = 4 * cp;
    // step-invariant bf16 B slab -> registers
    uint4 rb[KD / 8];
    #pragma unroll
    for (int j = 0; j < KD / 8; ++j)
        rb[j] = *(const uint4*)&Bb[(k0 + rw + 8 * j) * Wb + c0 + c4];
    // stage Q rows rg*32..+31 over [k0,k0+KD), fan-in-8 resolve
    const int qsz = QD << 7;
    for (int j = 0; j < (KD * 32) / 256; ++j) {
        int slot = j * 256 + tid;
        int row = slot / KD, kk = slot - row * KD;
        int g = (rg * 32 + row) * QD + k0 + kk;
        float2 q;
        if (first) {
            q = make_float2(Q0r[g], Q0i[g]);
        } else {
            q = make_float2(0.f, 0.f);
            #pragma unroll
            for (int pt = 0; pt < 8; ++pt) {
                float2 v = Qrd[pt * qsz + g];
                q.x += v.x; q.y += v.y;
            }
        }
        sQ[kk][row] = q;
    }
    for (int c = 0; c < KD / 16; ++c) {
        __syncthreads();
        *(uint4*)&sBu[rw][c4]     = rb[2 * c];
        *(uint4*)&sBu[rw + 8][c4] = rb[2 * c + 1];
        __syncthreads();
        #pragma unroll
        for (int kk = 0; kk < 16; ++kk) {
            float4 qA = *(const float4*)&sQ[c * 16 + kk][4 * rw];
            float4 qB = *(const float4*)&sQ[c * 16 + kk][4 * rw + 2];
            uint4 bu = *(const uint4*)&sBu[kk][c4];
            float qr[4] = {qA.x, qA.z, qB.x, qB.z};
            float qi[4] = {qA.y, qA.w, qB.y, qB.w};
            float br[4] = {UNPACK_R(bu.x), UNPACK_R(bu.y), UNPACK_R(bu.z), UNPACK_R(bu.w)};
            float bi[4] = {UNPACK_I(bu.x), UNPACK_I(bu.y), UNPACK_I(bu.z), UNPACK_I(bu.w)};
            #pragma unroll
            for (int r = 0; r < 4; ++r)
                #pragma unroll
                for (int cc = 0; cc < 4; ++cc) {
                    accr[4*r + cc] += qr[r] * br[cc] - qi[r] * bi[cc];
                    acci[4*r + cc] += qr[r] * bi[cc] + qi[r] * br[cc];
                }
        }
    }
}

// Grid 256 (full): [0,96) F: QF*A2b (4rg x 3cs x 8part, KD48)
//  [96,128)  Ee:  QF*BFb (4rg x 8part, KD48); part0 subtracts resolved
//            QH[:,:128]; ALL Ee blocks: resolve E_{s-1} pair -> Sm/S1 (init s=0)
//  [128,160) Eo1: QF*W1b -> Eo parts 0..7
//  [160,192) Eo2: -QH*Ab[:,:128] (KD32) -> Eo parts 8..15
//  [192,256) H:   QH*AH2b (4rg x 2cs x 8part, KD32)
__global__ __launch_bounds__(256, 1)
void dstep_kernel(Params P, int s, int base) {
    __shared__ __align__(16) unsigned int sBu[16][128];  // 8 KB
    __shared__ __align__(16) float2 sQ[48][33];          // 12.7 KB
    __shared__ float red[256];
    const int b = blockIdx.x + base, tid = threadIdx.x;
    const int rw = tid >> 5, cp = tid & 31;

    const float2* QFrd = (s & 1) ? P.QFp1 : P.QFp0;
    float2*       QFwr = (s & 1) ? P.QFp0 : P.QFp1;
    const float2* QHrd = (s & 1) ? P.QHp1 : P.QHp0;
    float2*       QHwr = (s & 1) ? P.QHp0 : P.QHp1;
    const float2* Eerd = (s & 1) ? P.Eep1 : P.Eep0;
    float2*       Eewr = (s & 1) ? P.Eep0 : P.Eep1;
    const float2* Eord = (s & 1) ? P.Eop1 : P.Eop0;
    float2*       Eowr = (s & 1) ? P.Eop0 : P.Eop1;
    const int first = (s == 0);

    float accr[16] = {}, acci[16] = {};

    if (b < 96) {                        // ---- F: QF*A2b
        int tile = b >> 3, part = b & 7;
        int rg = tile / 3, cs = tile - 3 * rg;
        dgemm_bf<48>(P.A2b, 384, cs << 7, part * 48, P.CFr, P.CFi, QFrd, 384,
                     first, rg, sBu, sQ, accr, acci);
        store16(QFwr + part * 49152, 384, rg * 32 + 4 * rw, (cs << 7) + 4 * cp, accr, acci, 1.f);
    } else if (b < 128) {                // ---- Ee: QF*BFb (+duties)
        int u = b - 96, rg = u >> 3, part = u & 7;
        // duty: resolve E_{s-1} pair into Sm/S1 (E_even, E_odd squared separately)
        if (first) {
            #pragma unroll
            for (int j = 0; j < 2; ++j) {
                int i = u * 512 + j * 256 + tid;
                P.Sm[i] = make_float2(P.DFr[i], P.DFi[i]);
            }
            if (b == 96 && tid == 0) { *P.S1 = 0.f; *P.S2 = 0.f; *P.SD = 0.f; *P.ticket = 0u; }
        } else {
            float v = 0.f;
            #pragma unroll
            for (int j = 0; j < 2; ++j) {
                int i = u * 512 + j * 256 + tid;
                float eer = 0.f, eei = 0.f, eor = 0.f, eoi = 0.f;
                #pragma unroll
                for (int pt = 0; pt < 8; ++pt) {
                    float2 e = Eerd[pt * 16384 + i];
                    eer += e.x; eei += e.y;
                }
                #pragma unroll
                for (int pt = 0; pt < 16; ++pt) {
                    float2 e = Eord[pt * 16384 + i];
                    eor += e.x; eoi += e.y;
                }
                float2 sm = P.Sm[i];
                P.Sm[i] = make_float2(sm.x + eer + eor, sm.y + eei + eoi);
                v += eer * eer + eei * eei + eor * eor + eoi * eoi;
            }
            float tot = block_reduce(v, red, tid);
            if (tid == 0) atomicAdd(P.S1, tot);
        }
        dgemm_bf<48>(P.BFb, 128, 0, part * 48, P.CFr, P.CFi, QFrd, 384,
                     first, rg, sBu, sQ, accr, acci);
        const int prow0 = rg * 32 + 4 * rw, pcol0 = 4 * cp;
        if (part == 0) {   // subtract resolved QH[:, :128] exactly once
            #pragma unroll
            for (int r = 0; r < 4; ++r) {
                int gbase = (prow0 + r) * 256 + pcol0;
                if (first) {
                    #pragma unroll
                    for (int cc = 0; cc < 4; ++cc) {
                        accr[4*r + cc] -= P.Cr[gbase + cc];
                        acci[4*r + cc] -= P.Ci[gbase + cc];
                    }
                } else {
                    #pragma unroll
                    for (int pt = 0; pt < 8; ++pt) {
                        const float2* qh = QHrd + pt * 32768;
                        #pragma unroll
                        for (int cc = 0; cc < 4; ++cc) {
                            float2 v = qh[gbase + cc];
                            accr[4*r + cc] -= v.x; acci[4*r + cc] -= v.y;
                        }
                    }
                }
            }
        }
        store16(Eewr + part * 16384, 128, prow0, pcol0, accr, acci, 1.f);
    } else if (b < 160) {                // ---- Eo1: QF*W1b
        int u = b - 128, rg = u >> 3, part = u & 7;
        dgemm_bf<48>(P.W1b, 128, 0, part * 48, P.CFr, P.CFi, QFrd, 384,
                     first, rg, sBu, sQ, accr, acci);
        store16(Eowr + part * 16384, 128, rg * 32 + 4 * rw, 4 * cp, accr, acci, 1.f);
    } else if (b < 192) {                // ---- Eo2: -QH*Ab[:, :128]
        int u = b - 160, rg = u >> 3, part = u & 7;
        dgemm_bf<32>(P.Ab, 256, 0, part * 32, P.Cr, P.Ci, QHrd, 256,
                     first, rg, sBu, sQ, accr, acci);
        store16(Eowr + (8 + part) * 16384, 128, rg * 32 + 4 * rw, 4 * cp, accr, acci, -1.f);
    } else {                             // ---- H: QH*AH2b
        int u = b - 192, tile = u >> 3, part = u & 7;
        int rg = tile >> 1, cs = tile & 1;
        dgemm_bf<32>(P.AH2b, 256, cs << 7, part * 32, P.Cr, P.Ci, QHrd, 256,
                     first, rg, sBu, sQ, accr, acci);
        store16(QHwr + part * 32768, 256, rg * 32 + 4 * rw, (cs << 7) + 4 * cp, accr, acci, 1.f);
    }
}

// --------- finalize: resolve E_7 pair, S1/S2/SD, ticketed out-write ---------
__global__ __launch_bounds__(256)
void finalize_kernel(Params P) {
    __shared__ float red[256];
    __shared__ unsigned int lastflag;
    const int b = blockIdx.x, tid = threadIdx.x;
    int i = (b << 8) + tid;
    float eer = 0.f, eei = 0.f, eor = 0.f, eoi = 0.f;
    #pragma unroll
    for (int pt = 0; pt < 8; ++pt) { float2 e = P.Eep0[pt * 16384 + i]; eer += e.x; eei += e.y; }
    #pragma unroll
    for (int pt = 0; pt < 16; ++pt) { float2 e = P.Eop0[pt * 16384 + i]; eor += e.x; eoi += e.y; }
    float2 sm = P.Sm[i];
    float smr = sm.x + eer + eor, smi = sm.y + eei + eoi;
    float dr = P.DFr[i], di = P.DFi[i];
    float t1 = block_reduce(eer * eer + eei * eei + eor * eor + eoi * eoi, red, tid);
    if (tid == 0) atomicAdd(P.S1, t1);
    float t2 = block_reduce(smr * smr + smi * smi, red, tid);
    if (tid == 0) atomicAdd(P.S2, t2);
    float t3 = block_reduce(dr * dr + di * di, red, tid);
    if (tid == 0) atomicAdd(P.SD, t3);
    __threadfence();
    __syncthreads();
    if (tid == 0)
        lastflag = (__hip_atomic_fetch_add(P.ticket, 1u, __ATOMIC_ACQ_REL,
                                           __HIP_MEMORY_SCOPE_AGENT) == 63u);
    __syncthreads();
    if (lastflag && tid == 0) {
        float S1 = __hip_atomic_load(P.S1, __ATOMIC_RELAXED, __HIP_MEMORY_SCOPE_AGENT);
        float S2 = __hip_atomic_load(P.S2, __ATOMIC_RELAXED, __HIP_MEMORY_SCOPE_AGENT);
        float SD = __hip_atomic_load(P.SD, __ATOMIC_RELAXED, __HIP_MEMORY_SCOPE_AGENT);
        P.out[0] = (99.0f * (S1 + SD) + S2) / 100.0f;
    }
}

extern "C" void kernel_launch(void* const* d_in, const int* in_sizes, int n_in,
                              void* d_out, int out_size, void* d_ws, size_t ws_size,
                              hipStream_t stream) {
    (void)in_sizes; (void)n_in; (void)out_size; (void)ws_size;
    char* ws = (char*)d_ws;
    Params h;
    h.Cr  = (const float*)d_in[0];
    h.Ci  = (const float*)d_in[1];
    h.Ar  = (const float*)d_in[2];
    h.Ai  = (const float*)d_in[3];
    h.AFr = (const float*)d_in[4];
    h.AFi = (const float*)d_in[5];
    h.BFr = (const float*)d_in[6];
    h.BFi = (const float*)d_in[7];
    h.CFr = (const float*)d_in[8];
    h.CFi = (const float*)d_in[9];
    h.DFr = (const float*)d_in[10];
    h.DFi = (const float*)d_in[11];
    // Region A [0, 8388608): pre1 partials, later overlaid by the p0 buffers
    // (pre partials are dead after pre2; p0 set first written at s=1).
    h.A2p  = (float2*)(ws + 0);          // 4*147456 f2 = 4718592 B
    h.W1p  = (float2*)(ws + 4718592);    // 4*49152  f2 = 1572864 B
    h.AH2p = (float2*)(ws + 6291456);    // 4*65536  f2 = 2097152 B
    h.QFp0 = (float2*)(ws + 0);          // 8*49152 f2 = 3145728 B
    h.QHp0 = (float2*)(ws + 3145728);    // 8*32768 f2 = 2097152 B
    h.Eep0 = (float2*)(ws + 5242880);    // 8*16384 f2 = 1048576 B
    h.Eop0 = (float2*)(ws + 6291456);    // 16*16384 f2 = 2097152 B
    // Region B [8388608, ...): persistent
    h.A2b  = (unsigned int*)(ws + 8388608);   // 589824
    h.W1b  = (unsigned int*)(ws + 8978432);   // 196608
    h.AH2b = (unsigned int*)(ws + 9175040);   // 262144
    h.BFb  = (unsigned int*)(ws + 9437184);   // 196608
    h.Ab   = (unsigned int*)(ws + 9633792);   // 262144
    h.QFp1 = (float2*)(ws + 9895936);         // 3145728
    h.QHp1 = (float2*)(ws + 13041664);        // 2097152
    h.Eep1 = (float2*)(ws + 15138816);        // 1048576
    h.Eop1 = (float2*)(ws + 16187392);        // 2097152
    h.Sm   = (float2*)(ws + 18284544);        // 131072
    h.S1   = (float*)(ws + 18415616);
    h.S2   = (float*)(ws + 18415620);
    h.SD   = (float*)(ws + 18415624);
    h.ticket = (unsigned int*)(ws + 18415628);
    h.out  = (float*)d_out;

    pre1_kernel<<<256, 256, 0, stream>>>(h);
    pre2_kernel<<<1472, 256, 0, stream>>>(h);
    for (int s = 0; s < 3; ++s)
        dstep_kernel<<<256, 256, 0, stream>>>(h, s, 0);
    // last double-step: E sections only (QF/QH advance would be dead work)
    dstep_kernel<<<96, 256, 0, stream>>>(h, 3, 96);
    finalize_kernel<<<64, 256, 0, stream>>>(h);
}